// Round 7
// baseline (354.703 us; speedup 1.0000x reference)
//
#include <hip/hip_runtime.h>

// VectorQuantizer: fp32 buffers, low-precision-valued data. in [32,64,64,64]
// NCHW, emb [512,64], out fp32. np-ref computes distances in fp32 -> argmin
// must match numpy bit-for-bit. Proven-correct numerics (R5/R6, absmax 0.0):
// hi/lo bf16 split (exact products), filter c2=(b2+4)-2*(xh.eh+xh.el+xl.eh),
// MARGIN 1e-4 >= filter-vs-numpy bound (~6.5e-5). R7: single MFMA pass with
// in-register top-2 per row (no phase-2 recompute), swizzled codebook so each
// B-load is 1KB contiguous + register double-buffer prefetch; ambiguous rows
// (gap<=MARGIN) resolved by wave-cooperative bit-exact numpy fp32 rescan.

#define NEMB 512
#define DIM 64
#define ROWS 64
#define MARGIN 1.0e-4f

typedef unsigned int u32;
typedef unsigned short u16;
typedef __attribute__((ext_vector_type(8))) short bf16x8;
typedef __attribute__((ext_vector_type(4))) float f32x4;

__device__ __forceinline__ u32 f2bfbits(float f) {  // fp32 -> bf16 bits (RNE)
  u32 u = __float_as_uint(f);
  return (u + 0x7FFFu + ((u >> 16) & 1u)) >> 16;
}
__device__ __forceinline__ float bfbits2f(u32 b) {
  return __uint_as_float(b << 16);
}

// ---- prep: swizzled hi/lo bf16 codebook + exact numpy-replica b2 ----
// Swizzle (u16 units): off(g,p,h,r,e) = g*2048 + p*1024 + h*512 + r*32 + e
//   g=row>>4, r=row&15, p=plane(0 hi,1 lo), h=k>>5, e=k&31.
// A wave's fragment load (16 rows x 16B at fixed h,p) is then 1KB contiguous.
__global__ void vq_prep(const float* __restrict__ emb, u16* __restrict__ swz,
                        float* __restrict__ b2) {
#pragma clang fp contract(off)
  const int n = blockIdx.x * 256 + threadIdx.x;
  if (n >= NEMB) return;
  const float* e = emb + n * DIM;
  float rr[8];
#pragma unroll
  for (int j = 0; j < 8; ++j) {
    float acc = e[j] * e[j];
#pragma unroll
    for (int i = 8; i < DIM; i += 8) acc = acc + e[i + j] * e[i + j];
    rr[j] = acc;
  }
  b2[n] = ((rr[0] + rr[1]) + (rr[2] + rr[3])) + ((rr[4] + rr[5]) + (rr[6] + rr[7]));
  const int g = n >> 4, r = n & 15;
  u16* gb = swz + (g << 11) + (r << 5);
#pragma unroll
  for (int k = 0; k < DIM; ++k) {
    const u32 h = f2bfbits(e[k]);
    const float res = e[k] - bfbits2f(h);  // exact (Sterbenz)
    const int off = ((k >> 5) << 9) + (k & 31);
    gb[off] = (u16)h;            // hi plane
    gb[1024 + off] = (u16)f2bfbits(res);  // lo plane
  }
}

// ---- main kernel: 64 rows/block; wave wv owns cols [wv*128, wv*128+128) ----
__global__ __launch_bounds__(256, 2) void vq_mfma(
    const float* __restrict__ in, const float* __restrict__ emb,
    const u16* __restrict__ swz, const float* __restrict__ b2g,
    float* __restrict__ out) {
#pragma clang fp contract(off)
  __shared__ float xs[ROWS][DIM + 2];
  __shared__ float a2s[ROWS];
  __shared__ float b2ps[NEMB];        // fl(b2 + 4) > 0
  __shared__ float wsv1[ROWS][4];     // per-wave row top-1 value
  __shared__ float wsv2[ROWS][4];     // per-wave row top-2 value
  __shared__ int wsi1[ROWS][4];       // per-wave row argmin
  __shared__ int win[ROWS];
  __shared__ int queue[ROWS];
  __shared__ int qcnt;

  const int tid = threadIdx.x;
  const int blk = blockIdx.x;
  const int b = blk >> 6;
  const int hw0 = (blk & 63) << 6;
  const float* xbase = in + ((size_t)b << 18) + hw0;

  for (int i = tid; i < NEMB; i += 256) b2ps[i] = b2g[i] + 4.0f;
  if (tid == 0) qcnt = 0;

  {  // stage x tile (64 consecutive floats per wave = coalesced)
    const int h = tid & 63, cg = tid >> 6;
#pragma unroll
    for (int i = 0; i < 16; ++i) {
      const int c = cg + (i << 2);
      xs[h][c] = xbase[((size_t)c << 12) + h];
    }
  }
  __syncthreads();

  if (tid < ROWS) {  // a2 numpy pairwise-8 replica (fallback path input)
    const float* x = xs[tid];
    float rr[8];
#pragma unroll
    for (int j = 0; j < 8; ++j) {
      float acc = x[j] * x[j];
#pragma unroll
      for (int i = 8; i < DIM; i += 8) acc = acc + x[i + j] * x[i + j];
      rr[j] = acc;
    }
    a2s[tid] = ((rr[0] + rr[1]) + (rr[2] + rr[3])) + ((rr[4] + rr[5]) + (rr[6] + rr[7]));
  }

  const int lane = tid & 63;
  const int wv = tid >> 6;
  const int rowl = lane & 15;  // column residue / A row residue
  const int quad = lane >> 4;  // k-octet / D row group

  // A fragments for all 4 row-tiles, hi/lo split: A[m=lane&15][k=quad*8+j]
  bf16x8 ah[4][2], al[4][2];
#pragma unroll
  for (int a = 0; a < 4; ++a) {
    const float* xr = xs[(a << 4) + rowl];
#pragma unroll
    for (int f = 0; f < 2; ++f) {
      const int k0 = (f << 5) + (quad << 3);
      bf16x8 vh, vl;
#pragma unroll
      for (int j = 0; j < 8; ++j) {
        const float xv = xr[k0 + j];
        const u32 h = f2bfbits(xv);
        const float res = xv - bfbits2f(h);  // exact
        vh[j] = (short)h;
        vl[j] = (short)f2bfbits(res);
      }
      ah[a][f] = vh;
      al[a][f] = vl;
    }
  }

  // ---- single pass: top-2 (value) + argmin per (tile,reg), 8 iters ----
  float v1[16], v2[16];
  int i1[16];
#pragma unroll
  for (int i = 0; i < 16; ++i) { v1[i] = 3.0e38f; v2[i] = 3.0e38f; i1[i] = 0; }

  const u16* wbase = swz + ((wv << 3) << 11);  // group wv*8
  const int off = (rowl << 5) + (quad << 3);

  bf16x8 nh0 = *(const bf16x8*)(wbase + off);
  bf16x8 nh1 = *(const bf16x8*)(wbase + 512 + off);
  bf16x8 nl0 = *(const bf16x8*)(wbase + 1024 + off);
  bf16x8 nl1 = *(const bf16x8*)(wbase + 1536 + off);

#pragma unroll
  for (int t = 0; t < 8; ++t) {
    const bf16x8 bh0 = nh0, bh1 = nh1, bl0 = nl0, bl1 = nl1;
    if (t < 7) {  // prefetch next group (1KB-contiguous wave loads)
      const u16* g2 = wbase + ((t + 1) << 11);
      nh0 = *(const bf16x8*)(g2 + off);
      nh1 = *(const bf16x8*)(g2 + 512 + off);
      nl0 = *(const bf16x8*)(g2 + 1024 + off);
      nl1 = *(const bf16x8*)(g2 + 1536 + off);
    }
    const int n = (wv << 7) + (t << 4) + rowl;
    const float b2p = b2ps[n];
#pragma unroll
    for (int a = 0; a < 4; ++a) {
      f32x4 acc = {0.f, 0.f, 0.f, 0.f};
      acc = __builtin_amdgcn_mfma_f32_16x16x32_bf16(ah[a][0], bh0, acc, 0, 0, 0);
      acc = __builtin_amdgcn_mfma_f32_16x16x32_bf16(ah[a][1], bh1, acc, 0, 0, 0);
      acc = __builtin_amdgcn_mfma_f32_16x16x32_bf16(ah[a][0], bl0, acc, 0, 0, 0);
      acc = __builtin_amdgcn_mfma_f32_16x16x32_bf16(ah[a][1], bl1, acc, 0, 0, 0);
      acc = __builtin_amdgcn_mfma_f32_16x16x32_bf16(al[a][0], bh0, acc, 0, 0, 0);
      acc = __builtin_amdgcn_mfma_f32_16x16x32_bf16(al[a][1], bh1, acc, 0, 0, 0);
#pragma unroll
      for (int r = 0; r < 4; ++r) {
        const int i = (a << 2) + r;
        const float c2 = fmaf(-2.0f, acc[r], b2p);
        const bool lt1 = c2 < v1[i];
        const bool lt2 = c2 < v2[i];
        v2[i] = lt1 ? v1[i] : (lt2 ? c2 : v2[i]);
        v1[i] = lt1 ? c2 : v1[i];
        i1[i] = lt1 ? n : i1[i];
      }
    }
  }

  // butterfly top-2 merge across the 16 column lanes (merged top-2 of
  // per-lane top-2s == exact top-2 of the union)
#pragma unroll
  for (int m = 1; m < 16; m <<= 1) {
#pragma unroll
    for (int i = 0; i < 16; ++i) {
      const float ov1 = __shfl_xor(v1[i], m);
      const float ov2 = __shfl_xor(v2[i], m);
      const int oi1 = __shfl_xor(i1[i], m);
      const float nv2 = fminf(fmaxf(v1[i], ov1), fminf(v2[i], ov2));
      const bool take = ov1 < v1[i];
      v1[i] = take ? ov1 : v1[i];
      i1[i] = take ? oi1 : i1[i];
      v2[i] = nv2;
    }
  }
  if (rowl == 0) {  // one lane per (quad) publishes its 16 rows
#pragma unroll
    for (int a = 0; a < 4; ++a)
#pragma unroll
      for (int r = 0; r < 4; ++r) {
        const int row = (a << 4) + (quad << 2) + r;
        const int i = (a << 2) + r;
        wsv1[row][wv] = v1[i];
        wsv2[row][wv] = v2[i];
        wsi1[row][wv] = i1[i];
      }
  }
  __syncthreads();

  // ---- cross-wave merge, flag ambiguous rows ----
  if (tid < ROWS) {
    float m1 = wsv1[tid][0], m2 = wsv2[tid][0];
    int mi = wsi1[tid][0];
#pragma unroll
    for (int w = 1; w < 4; ++w) {
      const float u1 = wsv1[tid][w], u2 = wsv2[tid][w];
      const int j1 = wsi1[tid][w];
      if (u1 < m1) { m2 = fminf(m1, u2); m1 = u1; mi = j1; }
      else { m2 = fminf(m2, u1); }
    }
    win[tid] = mi;
    if (m2 <= m1 + MARGIN) {  // ambiguous: exact rescan required
      const int p = atomicAdd(&qcnt, 1);
      queue[p] = tid;
    }
  }
  __syncthreads();

  // ---- rare fallback: wave-cooperative bit-exact numpy fp32 rescan ----
  const int nq = qcnt;
  for (int qi = wv; qi < nq; qi += 4) {
    const int row = queue[qi];
    const float a2 = a2s[row];
    const float* x = xs[row];  // broadcast LDS reads
    float bd = 3.0e38f;
    int bi = 1 << 30;
#pragma unroll
    for (int c = 0; c < 8; ++c) {
      const int k = (c << 6) + lane;
      const float* e = emb + (k << 6);
      float acc = 0.f;
#pragma unroll
      for (int j = 0; j < DIM; ++j) acc = fmaf(x[j], e[j], acc);
      const float tt = a2 + b2g[k];  // fl(a2+b2)
      const float u = 2.0f * acc;    // fl(2ab)
      const float d = tt - u;        // fl(t-u)
      if (d < bd || (d == bd && k < bi)) { bd = d; bi = k; }
    }
#pragma unroll
    for (int m = 1; m < 64; m <<= 1) {  // numpy first-min tie rule
      const float od = __shfl_xor(bd, m);
      const int oi = __shfl_xor(bi, m);
      if (od < bd || (od == bd && oi < bi)) { bd = od; bi = oi; }
    }
    if (lane == 0) win[row] = bi;
  }
  __syncthreads();

  {  // output: fl(x + fl(q-x)), coalesced stores
    const int h = tid & 63, cg = tid >> 6;
    float* obase = out + ((size_t)b << 18) + hw0;
    const float* eW = emb + win[h] * DIM;
#pragma unroll
    for (int i = 0; i < 16; ++i) {
      const int c = cg + (i << 2);
      const float xv = xs[h][c];
      const float qv = eW[c];
      obase[((size_t)c << 12) + h] = xv + (qv - xv);
    }
  }
}

// ---- fallback (R3, passed absmax 0.0): used only if ws too small ----
__global__ __launch_bounds__(256, 2) void vq_exact(
    const float* __restrict__ in, const float* __restrict__ emb,
    float* __restrict__ out, int nvec) {
#pragma clang fp contract(off)
  __shared__ float b2s[NEMB];
  for (int r = threadIdx.x; r < NEMB; r += 256) {
    const float* e = emb + r * DIM;
    float rr[8];
#pragma unroll
    for (int j = 0; j < 8; ++j) {
      float acc = e[j] * e[j];
#pragma unroll
      for (int i = 8; i < DIM; i += 8) acc = acc + e[i + j] * e[i + j];
      rr[j] = acc;
    }
    b2s[r] = ((rr[0] + rr[1]) + (rr[2] + rr[3])) + ((rr[4] + rr[5]) + (rr[6] + rr[7]));
  }
  __syncthreads();
  const int vec = blockIdx.x * 256 + threadIdx.x;
  if (vec >= nvec) return;
  const int b = vec >> 12, hw = vec & 4095;
  const float* xp = in + ((size_t)b << 18) + hw;
  float x[DIM];
#pragma unroll
  for (int j = 0; j < DIM; ++j) x[j] = xp[(size_t)j << 12];
  float a2;
  {
    float rr[8];
#pragma unroll
    for (int j = 0; j < 8; ++j) {
      float acc = x[j] * x[j];
#pragma unroll
      for (int i = 8; i < DIM; i += 8) acc = acc + x[i + j] * x[i + j];
      rr[j] = acc;
    }
    a2 = ((rr[0] + rr[1]) + (rr[2] + rr[3])) + ((rr[4] + rr[5]) + (rr[6] + rr[7]));
  }
  float best = 3.0e38f;
  int bi = 0;
  for (int k0 = 0; k0 < NEMB; k0 += 4) {
    const float *e0 = emb + ((k0 + 0) << 6), *e1 = emb + ((k0 + 1) << 6);
    const float *e2 = emb + ((k0 + 2) << 6), *e3 = emb + ((k0 + 3) << 6);
    float c0 = 0.f, c1 = 0.f, c2 = 0.f, c3 = 0.f;
#pragma unroll
    for (int j = 0; j < DIM; ++j) {
      const float xj = x[j];
      c0 = fmaf(xj, e0[j], c0); c1 = fmaf(xj, e1[j], c1);
      c2 = fmaf(xj, e2[j], c2); c3 = fmaf(xj, e3[j], c3);
    }
    float cc[4] = {c0, c1, c2, c3};
#pragma unroll
    for (int q = 0; q < 4; ++q) {
      const float t = a2 + b2s[k0 + q];
      const float u = 2.0f * cc[q];
      const float d = t - u;
      if (d < best) { best = d; bi = k0 + q; }
    }
  }
  const float* ew = emb + (bi << 6);
  float* op = out + ((size_t)b << 18) + hw;
#pragma unroll
  for (int c = 0; c < DIM; ++c) {
    const float xv = x[c];
    op[(size_t)c << 12] = xv + (ew[c] - xv);
  }
}

extern "C" void kernel_launch(void* const* d_in, const int* in_sizes, int n_in,
                              void* d_out, int out_size, void* d_ws, size_t ws_size,
                              hipStream_t stream) {
  const float* in;
  const float* emb;
  int in_elems;
  if (n_in >= 2 && in_sizes[0] == NEMB * DIM && in_sizes[1] != NEMB * DIM) {
    emb = (const float*)d_in[0]; in = (const float*)d_in[1]; in_elems = in_sizes[1];
  } else {
    in = (const float*)d_in[0]; emb = (const float*)d_in[1]; in_elems = in_sizes[0];
  }
  float* out = (float*)d_out;
  const int nvec = in_elems / DIM;
  const size_t swzB = (size_t)NEMB * DIM * 2 * sizeof(u16);  // hi+lo swizzled
  const size_t need = swzB + NEMB * sizeof(float);

  if (ws_size >= need && d_ws != nullptr && (nvec % ROWS) == 0 &&
      (in_elems % (DIM * 4096)) == 0) {
    u16* swz = (u16*)d_ws;
    float* b2 = (float*)((char*)d_ws + swzB);
    vq_prep<<<dim3(2), dim3(256), 0, stream>>>(emb, swz, b2);
    vq_mfma<<<dim3(nvec / ROWS), dim3(256), 0, stream>>>(in, emb, swz, b2, out);
  } else {
    vq_exact<<<dim3((nvec + 255) / 256), dim3(256), 0, stream>>>(in, emb, out, nvec);
  }
}

// Round 8
// 312.573 us; speedup vs baseline: 1.1348x; 1.1348x over previous
//
#include <hip/hip_runtime.h>

// VectorQuantizer: fp32 buffers, low-precision-valued data. in [32,64,64,64]
// NCHW, emb [512,64], out fp32. np-ref computes distances in fp32 -> argmin
// must match numpy bit-for-bit. Proven numerics (R5/R6, absmax 0.0): hi/lo
// bf16 split (exact products), filter c2=(b2+4)-2*(xh.eh+xh.el+xl.eh),
// MARGIN 1e-4 >= filter-vs-numpy bound; ambiguous rows (top2 gap<=MARGIN)
// resolved by wave-cooperative bit-exact numpy fp32 rescan.
// R8: fix R7's scratch spill (WRITE_SIZE 318MB; empirical cap ~256/arg2).
// Wave owns 2 row-tiles x 256 cols -> ~110 live VGPRs; launch_bounds(256,1).

#define NEMB 512
#define DIM 64
#define ROWS 64
#define MARGIN 1.0e-4f

typedef unsigned int u32;
typedef unsigned short u16;
typedef __attribute__((ext_vector_type(8))) short bf16x8;
typedef __attribute__((ext_vector_type(4))) float f32x4;

__device__ __forceinline__ u32 f2bfbits(float f) {  // fp32 -> bf16 bits (RNE)
  u32 u = __float_as_uint(f);
  return (u + 0x7FFFu + ((u >> 16) & 1u)) >> 16;
}
__device__ __forceinline__ float bfbits2f(u32 b) {
  return __uint_as_float(b << 16);
}

// ---- prep: swizzled hi/lo bf16 codebook + exact numpy-replica b2 ----
// off(g,p,f,r,e) = g*2048 + p*1024 + f*512 + r*32 + e   (u16 units)
//   g=row>>4, r=row&15, p=plane(0 hi,1 lo), f=k>>5, e=k&31.
// A wave's 16-row fragment load at fixed (p,f) is 1KB contiguous.
__global__ void vq_prep(const float* __restrict__ emb, u16* __restrict__ swz,
                        float* __restrict__ b2) {
#pragma clang fp contract(off)
  const int n = blockIdx.x * 256 + threadIdx.x;
  if (n >= NEMB) return;
  const float* e = emb + n * DIM;
  float rr[8];
#pragma unroll
  for (int j = 0; j < 8; ++j) {
    float acc = e[j] * e[j];
#pragma unroll
    for (int i = 8; i < DIM; i += 8) acc = acc + e[i + j] * e[i + j];
    rr[j] = acc;
  }
  b2[n] = ((rr[0] + rr[1]) + (rr[2] + rr[3])) + ((rr[4] + rr[5]) + (rr[6] + rr[7]));
  const int g = n >> 4, r = n & 15;
  u16* gb = swz + (g << 11) + (r << 5);
#pragma unroll
  for (int k = 0; k < DIM; ++k) {
    const u32 h = f2bfbits(e[k]);
    const float res = e[k] - bfbits2f(h);  // exact (Sterbenz)
    const int off = ((k >> 5) << 9) + (k & 31);
    gb[off] = (u16)h;                     // hi plane
    gb[1024 + off] = (u16)f2bfbits(res);  // lo plane
  }
}

// ---- main kernel: 64 rows/block.
// wave wv: row-half rh=wv&1 (tiles 2rh,2rh+1), col-half ch=wv>>1 (256 cols).
__global__ __launch_bounds__(256, 1) void vq_mfma(
    const float* __restrict__ in, const float* __restrict__ emb,
    const u16* __restrict__ swz, const float* __restrict__ b2g,
    float* __restrict__ out) {
#pragma clang fp contract(off)
  __shared__ float xs[ROWS][DIM + 2];
  __shared__ float a2s[ROWS];
  __shared__ float b2ps[NEMB];     // fl(b2 + 4) > 0
  __shared__ float wsv1[ROWS][2];  // per-col-half row top-1
  __shared__ float wsv2[ROWS][2];  // per-col-half row top-2
  __shared__ int wsi1[ROWS][2];    // per-col-half row argmin
  __shared__ int win[ROWS];
  __shared__ int queue[ROWS];
  __shared__ int qcnt;

  const int tid = threadIdx.x;
  const int blk = blockIdx.x;
  const int b = blk >> 6;
  const int hw0 = (blk & 63) << 6;
  const float* xbase = in + ((size_t)b << 18) + hw0;

  for (int i = tid; i < NEMB; i += 256) b2ps[i] = b2g[i] + 4.0f;
  if (tid == 0) qcnt = 0;

  {  // stage x tile (64 consecutive floats per wave = coalesced)
    const int h = tid & 63, cg = tid >> 6;
#pragma unroll
    for (int i = 0; i < 16; ++i) {
      const int c = cg + (i << 2);
      xs[h][c] = xbase[((size_t)c << 12) + h];
    }
  }
  __syncthreads();

  if (tid < ROWS) {  // a2 numpy pairwise-8 replica (fallback input)
    const float* x = xs[tid];
    float rr[8];
#pragma unroll
    for (int j = 0; j < 8; ++j) {
      float acc = x[j] * x[j];
#pragma unroll
      for (int i = 8; i < DIM; i += 8) acc = acc + x[i + j] * x[i + j];
      rr[j] = acc;
    }
    a2s[tid] = ((rr[0] + rr[1]) + (rr[2] + rr[3])) + ((rr[4] + rr[5]) + (rr[6] + rr[7]));
  }

  const int lane = tid & 63;
  const int wv = tid >> 6;
  const int rh = wv & 1;   // row-half
  const int ch = wv >> 1;  // col-half
  const int rowl = lane & 15;
  const int quad = lane >> 4;

  // A fragments for this wave's 2 row-tiles: A[m=lane&15][k=quad*8+j]
  bf16x8 ah[2][2], al[2][2];
#pragma unroll
  for (int ta = 0; ta < 2; ++ta) {
    const int a = (rh << 1) + ta;
    const float* xr = xs[(a << 4) + rowl];
#pragma unroll
    for (int f = 0; f < 2; ++f) {
      const int k0 = (f << 5) + (quad << 3);
      bf16x8 vh, vl;
#pragma unroll
      for (int j = 0; j < 8; ++j) {
        const float xv = xr[k0 + j];
        const u32 h = f2bfbits(xv);
        const float res = xv - bfbits2f(h);  // exact
        vh[j] = (short)h;
        vl[j] = (short)f2bfbits(res);
      }
      ah[ta][f] = vh;
      al[ta][f] = vl;
    }
  }

  // ---- single pass over 256 cols: top-2 + argmin per (tile,reg) ----
  float v1[8], v2[8];
  int i1[8];
#pragma unroll
  for (int i = 0; i < 8; ++i) { v1[i] = 3.0e38f; v2[i] = 3.0e38f; i1[i] = 0; }

  const u16* cbase = swz + ((size_t)(ch << 4) << 11);
  const int off = (rowl << 5) + (quad << 3);

  for (int t = 0; t < 16; ++t) {
    const u16* gb = cbase + (t << 11);
    const bf16x8 bh0 = *(const bf16x8*)(gb + off);
    const bf16x8 bh1 = *(const bf16x8*)(gb + 512 + off);
    const bf16x8 bl0 = *(const bf16x8*)(gb + 1024 + off);
    const bf16x8 bl1 = *(const bf16x8*)(gb + 1536 + off);
    const int n = (ch << 8) + (t << 4) + rowl;
    const float b2p = b2ps[n];
#pragma unroll
    for (int ta = 0; ta < 2; ++ta) {
      f32x4 acc = {0.f, 0.f, 0.f, 0.f};
      acc = __builtin_amdgcn_mfma_f32_16x16x32_bf16(ah[ta][0], bh0, acc, 0, 0, 0);
      acc = __builtin_amdgcn_mfma_f32_16x16x32_bf16(ah[ta][1], bh1, acc, 0, 0, 0);
      acc = __builtin_amdgcn_mfma_f32_16x16x32_bf16(ah[ta][0], bl0, acc, 0, 0, 0);
      acc = __builtin_amdgcn_mfma_f32_16x16x32_bf16(ah[ta][1], bl1, acc, 0, 0, 0);
      acc = __builtin_amdgcn_mfma_f32_16x16x32_bf16(al[ta][0], bh0, acc, 0, 0, 0);
      acc = __builtin_amdgcn_mfma_f32_16x16x32_bf16(al[ta][1], bh1, acc, 0, 0, 0);
#pragma unroll
      for (int r = 0; r < 4; ++r) {
        const int i = (ta << 2) + r;
        const float c2 = fmaf(-2.0f, acc[r], b2p);
        const bool lt1 = c2 < v1[i];
        const bool lt2 = c2 < v2[i];
        v2[i] = lt1 ? v1[i] : (lt2 ? c2 : v2[i]);
        v1[i] = lt1 ? c2 : v1[i];
        i1[i] = lt1 ? n : i1[i];
      }
    }
  }

  // butterfly top-2 merge across the 16 column lanes
#pragma unroll
  for (int m = 1; m < 16; m <<= 1) {
#pragma unroll
    for (int i = 0; i < 8; ++i) {
      const float ov1 = __shfl_xor(v1[i], m);
      const float ov2 = __shfl_xor(v2[i], m);
      const int oi1 = __shfl_xor(i1[i], m);
      const float nv2 = fminf(fmaxf(v1[i], ov1), fminf(v2[i], ov2));
      const bool take = ov1 < v1[i];
      v1[i] = take ? ov1 : v1[i];
      i1[i] = take ? oi1 : i1[i];
      v2[i] = nv2;
    }
  }
  if (rowl == 0) {  // publish per col-half slot
#pragma unroll
    for (int ta = 0; ta < 2; ++ta)
#pragma unroll
      for (int r = 0; r < 4; ++r) {
        const int row = (((rh << 1) + ta) << 4) + (quad << 2) + r;
        const int i = (ta << 2) + r;
        wsv1[row][ch] = v1[i];
        wsv2[row][ch] = v2[i];
        wsi1[row][ch] = i1[i];
      }
  }
  __syncthreads();

  // ---- cross-half merge, flag ambiguous rows ----
  if (tid < ROWS) {
    float m1 = wsv1[tid][0], m2 = wsv2[tid][0];
    int mi = wsi1[tid][0];
    const float u1 = wsv1[tid][1], u2 = wsv2[tid][1];
    const int j1 = wsi1[tid][1];
    if (u1 < m1) { m2 = fminf(m1, u2); m1 = u1; mi = j1; }
    else { m2 = fminf(m2, u1); }
    win[tid] = mi;
    if (m2 <= m1 + MARGIN) {  // ambiguous: exact rescan required
      const int p = atomicAdd(&qcnt, 1);
      queue[p] = tid;
    }
  }
  __syncthreads();

  // ---- rare fallback: wave-cooperative bit-exact numpy fp32 rescan ----
  const int nq = qcnt;
  for (int qi = wv; qi < nq; qi += 4) {
    const int row = queue[qi];
    const float a2 = a2s[row];
    const float* x = xs[row];  // broadcast LDS reads
    float bd = 3.0e38f;
    int bi = 1 << 30;
#pragma unroll
    for (int c = 0; c < 8; ++c) {
      const int k = (c << 6) + lane;
      const float* e = emb + (k << 6);
      float acc = 0.f;
#pragma unroll
      for (int j = 0; j < DIM; ++j) acc = fmaf(x[j], e[j], acc);
      const float tt = a2 + b2g[k];  // fl(a2+b2)
      const float u = 2.0f * acc;    // fl(2ab)
      const float d = tt - u;        // fl(t-u)
      if (d < bd || (d == bd && k < bi)) { bd = d; bi = k; }
    }
#pragma unroll
    for (int m = 1; m < 64; m <<= 1) {  // numpy first-min tie rule
      const float od = __shfl_xor(bd, m);
      const int oi = __shfl_xor(bi, m);
      if (od < bd || (od == bd && oi < bi)) { bd = od; bi = oi; }
    }
    if (lane == 0) win[row] = bi;
  }
  __syncthreads();

  {  // output: fl(x + fl(q-x)), coalesced stores
    const int h = tid & 63, cg = tid >> 6;
    float* obase = out + ((size_t)b << 18) + hw0;
    const float* eW = emb + win[h] * DIM;
#pragma unroll
    for (int i = 0; i < 16; ++i) {
      const int c = cg + (i << 2);
      const float xv = xs[h][c];
      const float qv = eW[c];
      obase[((size_t)c << 12) + h] = xv + (qv - xv);
    }
  }
}

// ---- fallback (R3, passed absmax 0.0): used only if ws too small ----
__global__ __launch_bounds__(256, 2) void vq_exact(
    const float* __restrict__ in, const float* __restrict__ emb,
    float* __restrict__ out, int nvec) {
#pragma clang fp contract(off)
  __shared__ float b2s[NEMB];
  for (int r = threadIdx.x; r < NEMB; r += 256) {
    const float* e = emb + r * DIM;
    float rr[8];
#pragma unroll
    for (int j = 0; j < 8; ++j) {
      float acc = e[j] * e[j];
#pragma unroll
      for (int i = 8; i < DIM; i += 8) acc = acc + e[i + j] * e[i + j];
      rr[j] = acc;
    }
    b2s[r] = ((rr[0] + rr[1]) + (rr[2] + rr[3])) + ((rr[4] + rr[5]) + (rr[6] + rr[7]));
  }
  __syncthreads();
  const int vec = blockIdx.x * 256 + threadIdx.x;
  if (vec >= nvec) return;
  const int b = vec >> 12, hw = vec & 4095;
  const float* xp = in + ((size_t)b << 18) + hw;
  float x[DIM];
#pragma unroll
  for (int j = 0; j < DIM; ++j) x[j] = xp[(size_t)j << 12];
  float a2;
  {
    float rr[8];
#pragma unroll
    for (int j = 0; j < 8; ++j) {
      float acc = x[j] * x[j];
#pragma unroll
      for (int i = 8; i < DIM; i += 8) acc = acc + x[i + j] * x[i + j];
      rr[j] = acc;
    }
    a2 = ((rr[0] + rr[1]) + (rr[2] + rr[3])) + ((rr[4] + rr[5]) + (rr[6] + rr[7]));
  }
  float best = 3.0e38f;
  int bi = 0;
  for (int k0 = 0; k0 < NEMB; k0 += 4) {
    const float *e0 = emb + ((k0 + 0) << 6), *e1 = emb + ((k0 + 1) << 6);
    const float *e2 = emb + ((k0 + 2) << 6), *e3 = emb + ((k0 + 3) << 6);
    float c0 = 0.f, c1 = 0.f, c2 = 0.f, c3 = 0.f;
#pragma unroll
    for (int j = 0; j < DIM; ++j) {
      const float xj = x[j];
      c0 = fmaf(xj, e0[j], c0); c1 = fmaf(xj, e1[j], c1);
      c2 = fmaf(xj, e2[j], c2); c3 = fmaf(xj, e3[j], c3);
    }
    float cc[4] = {c0, c1, c2, c3};
#pragma unroll
    for (int q = 0; q < 4; ++q) {
      const float t = a2 + b2s[k0 + q];
      const float u = 2.0f * cc[q];
      const float d = t - u;
      if (d < best) { best = d; bi = k0 + q; }
    }
  }
  const float* ew = emb + (bi << 6);
  float* op = out + ((size_t)b << 18) + hw;
#pragma unroll
  for (int c = 0; c < DIM; ++c) {
    const float xv = x[c];
    op[(size_t)c << 12] = xv + (ew[c] - xv);
  }
}

extern "C" void kernel_launch(void* const* d_in, const int* in_sizes, int n_in,
                              void* d_out, int out_size, void* d_ws, size_t ws_size,
                              hipStream_t stream) {
  const float* in;
  const float* emb;
  int in_elems;
  if (n_in >= 2 && in_sizes[0] == NEMB * DIM && in_sizes[1] != NEMB * DIM) {
    emb = (const float*)d_in[0]; in = (const float*)d_in[1]; in_elems = in_sizes[1];
  } else {
    in = (const float*)d_in[0]; emb = (const float*)d_in[1]; in_elems = in_sizes[0];
  }
  float* out = (float*)d_out;
  const int nvec = in_elems / DIM;
  const size_t swzB = (size_t)NEMB * DIM * 2 * sizeof(u16);  // hi+lo swizzled
  const size_t need = swzB + NEMB * sizeof(float);

  if (ws_size >= need && d_ws != nullptr && (nvec % ROWS) == 0 &&
      (in_elems % (DIM * 4096)) == 0) {
    u16* swz = (u16*)d_ws;
    float* b2 = (float*)((char*)d_ws + swzB);
    vq_prep<<<dim3(2), dim3(256), 0, stream>>>(emb, swz, b2);
    vq_mfma<<<dim3(nvec / ROWS), dim3(256), 0, stream>>>(in, emb, swz, b2, out);
  } else {
    vq_exact<<<dim3((nvec + 255) / 256), dim3(256), 0, stream>>>(in, emb, out, nvec);
  }
}

// Round 9
// 193.618 us; speedup vs baseline: 1.8320x; 1.6144x over previous
//
#include <hip/hip_runtime.h>

// VectorQuantizer: fp32 buffers, low-precision-valued data. in [32,64,64,64]
// NCHW, emb [512,64], out fp32. np-ref computes distances in fp32 -> argmin
// must match numpy bit-for-bit. Proven numerics (R5/R6/R8, absmax 0.0): hi/lo
// bf16 split (exact products), filter c2=(b2+4)-2*(xh.eh+xh.el+xl.eh),
// MARGIN 1e-4 >= filter-vs-numpy bound; ambiguous rows (top2 gap<=MARGIN)
// resolved by wave-cooperative bit-exact numpy fp32 rescan.
// R9: kill the scratch spill. R8's t-loop was fully unrolled -> backend
// hoisted 64 B-frag loads -> ~256 transient VGPRs -> persistent state spilled
// (WRITE_SIZE 160MB vs 32MB output). Pin with #pragma unroll 1 + manual
// 1-deep prefetch (clamped index, branchless). ~140 live VGPRs -> no spill.

#define NEMB 512
#define DIM 64
#define ROWS 64
#define MARGIN 1.0e-4f

typedef unsigned int u32;
typedef unsigned short u16;
typedef __attribute__((ext_vector_type(8))) short bf16x8;
typedef __attribute__((ext_vector_type(4))) float f32x4;

__device__ __forceinline__ u32 f2bfbits(float f) {  // fp32 -> bf16 bits (RNE)
  u32 u = __float_as_uint(f);
  return (u + 0x7FFFu + ((u >> 16) & 1u)) >> 16;
}
__device__ __forceinline__ float bfbits2f(u32 b) {
  return __uint_as_float(b << 16);
}

// ---- prep: swizzled hi/lo bf16 codebook + exact numpy-replica b2 ----
// off(g,p,f,r,e) = g*2048 + p*1024 + f*512 + r*32 + e   (u16 units)
//   g=row>>4, r=row&15, p=plane(0 hi,1 lo), f=k>>5, e=k&31.
// A wave's 16-row fragment load at fixed (p,f) is 1KB contiguous.
__global__ void vq_prep(const float* __restrict__ emb, u16* __restrict__ swz,
                        float* __restrict__ b2) {
#pragma clang fp contract(off)
  const int n = blockIdx.x * 256 + threadIdx.x;
  if (n >= NEMB) return;
  const float* e = emb + n * DIM;
  float rr[8];
#pragma unroll
  for (int j = 0; j < 8; ++j) {
    float acc = e[j] * e[j];
#pragma unroll
    for (int i = 8; i < DIM; i += 8) acc = acc + e[i + j] * e[i + j];
    rr[j] = acc;
  }
  b2[n] = ((rr[0] + rr[1]) + (rr[2] + rr[3])) + ((rr[4] + rr[5]) + (rr[6] + rr[7]));
  const int g = n >> 4, r = n & 15;
  u16* gb = swz + (g << 11) + (r << 5);
#pragma unroll
  for (int k = 0; k < DIM; ++k) {
    const u32 h = f2bfbits(e[k]);
    const float res = e[k] - bfbits2f(h);  // exact (Sterbenz)
    const int off = ((k >> 5) << 9) + (k & 31);
    gb[off] = (u16)h;                     // hi plane
    gb[1024 + off] = (u16)f2bfbits(res);  // lo plane
  }
}

// ---- main kernel: 64 rows/block.
// wave wv: row-half rh=wv&1 (tiles 2rh,2rh+1), col-half ch=wv>>1 (256 cols).
__global__ __launch_bounds__(256, 1) void vq_mfma(
    const float* __restrict__ in, const float* __restrict__ emb,
    const u16* __restrict__ swz, const float* __restrict__ b2g,
    float* __restrict__ out) {
#pragma clang fp contract(off)
  __shared__ float xs[ROWS][DIM + 2];
  __shared__ float a2s[ROWS];
  __shared__ float b2ps[NEMB];     // fl(b2 + 4) > 0
  __shared__ float wsv1[ROWS][2];  // per-col-half row top-1
  __shared__ float wsv2[ROWS][2];  // per-col-half row top-2
  __shared__ int wsi1[ROWS][2];    // per-col-half row argmin
  __shared__ int win[ROWS];
  __shared__ int queue[ROWS];
  __shared__ int qcnt;

  const int tid = threadIdx.x;
  const int blk = blockIdx.x;
  const int b = blk >> 6;
  const int hw0 = (blk & 63) << 6;
  const float* xbase = in + ((size_t)b << 18) + hw0;

  for (int i = tid; i < NEMB; i += 256) b2ps[i] = b2g[i] + 4.0f;
  if (tid == 0) qcnt = 0;

  {  // stage x tile (64 consecutive floats per wave = coalesced)
    const int h = tid & 63, cg = tid >> 6;
#pragma unroll
    for (int i = 0; i < 16; ++i) {
      const int c = cg + (i << 2);
      xs[h][c] = xbase[((size_t)c << 12) + h];
    }
  }
  __syncthreads();

  if (tid < ROWS) {  // a2 numpy pairwise-8 replica (fallback input)
    const float* x = xs[tid];
    float rr[8];
#pragma unroll
    for (int j = 0; j < 8; ++j) {
      float acc = x[j] * x[j];
#pragma unroll
      for (int i = 8; i < DIM; i += 8) acc = acc + x[i + j] * x[i + j];
      rr[j] = acc;
    }
    a2s[tid] = ((rr[0] + rr[1]) + (rr[2] + rr[3])) + ((rr[4] + rr[5]) + (rr[6] + rr[7]));
  }

  const int lane = tid & 63;
  const int wv = tid >> 6;
  const int rh = wv & 1;   // row-half
  const int ch = wv >> 1;  // col-half
  const int rowl = lane & 15;
  const int quad = lane >> 4;

  // A fragments for this wave's 2 row-tiles: A[m=lane&15][k=quad*8+j]
  bf16x8 ah[2][2], al[2][2];
#pragma unroll
  for (int ta = 0; ta < 2; ++ta) {
    const int a = (rh << 1) + ta;
    const float* xr = xs[(a << 4) + rowl];
#pragma unroll
    for (int f = 0; f < 2; ++f) {
      const int k0 = (f << 5) + (quad << 3);
      bf16x8 vh, vl;
#pragma unroll
      for (int j = 0; j < 8; ++j) {
        const float xv = xr[k0 + j];
        const u32 h = f2bfbits(xv);
        const float res = xv - bfbits2f(h);  // exact
        vh[j] = (short)h;
        vl[j] = (short)f2bfbits(res);
      }
      ah[ta][f] = vh;
      al[ta][f] = vl;
    }
  }

  // ---- single pass over 256 cols: top-2 + argmin per (tile,reg) ----
  float v1[8], v2[8];
  int i1[8];
#pragma unroll
  for (int i = 0; i < 8; ++i) { v1[i] = 3.0e38f; v2[i] = 3.0e38f; i1[i] = 0; }

  const u16* cbase = swz + ((size_t)(ch << 4) << 11);
  const int off = (rowl << 5) + (quad << 3);

  // preload group 0; rolled loop (unroll 1!) with 1-deep clamped prefetch
  bf16x8 nh0 = *(const bf16x8*)(cbase + off);
  bf16x8 nh1 = *(const bf16x8*)(cbase + 512 + off);
  bf16x8 nl0 = *(const bf16x8*)(cbase + 1024 + off);
  bf16x8 nl1 = *(const bf16x8*)(cbase + 1536 + off);

#pragma unroll 1
  for (int t = 0; t < 16; ++t) {
    const bf16x8 bh0 = nh0, bh1 = nh1, bl0 = nl0, bl1 = nl1;
    {  // prefetch next group (clamped at the end: harmless re-load)
      const int tn = t < 15 ? t + 1 : 15;
      const u16* gb = cbase + (tn << 11);
      nh0 = *(const bf16x8*)(gb + off);
      nh1 = *(const bf16x8*)(gb + 512 + off);
      nl0 = *(const bf16x8*)(gb + 1024 + off);
      nl1 = *(const bf16x8*)(gb + 1536 + off);
    }
    const int n = (ch << 8) + (t << 4) + rowl;
    const float b2p = b2ps[n];
#pragma unroll
    for (int ta = 0; ta < 2; ++ta) {
      f32x4 acc = {0.f, 0.f, 0.f, 0.f};
      acc = __builtin_amdgcn_mfma_f32_16x16x32_bf16(ah[ta][0], bh0, acc, 0, 0, 0);
      acc = __builtin_amdgcn_mfma_f32_16x16x32_bf16(ah[ta][1], bh1, acc, 0, 0, 0);
      acc = __builtin_amdgcn_mfma_f32_16x16x32_bf16(ah[ta][0], bl0, acc, 0, 0, 0);
      acc = __builtin_amdgcn_mfma_f32_16x16x32_bf16(ah[ta][1], bl1, acc, 0, 0, 0);
      acc = __builtin_amdgcn_mfma_f32_16x16x32_bf16(al[ta][0], bh0, acc, 0, 0, 0);
      acc = __builtin_amdgcn_mfma_f32_16x16x32_bf16(al[ta][1], bh1, acc, 0, 0, 0);
#pragma unroll
      for (int r = 0; r < 4; ++r) {
        const int i = (ta << 2) + r;
        const float c2 = fmaf(-2.0f, acc[r], b2p);
        const bool lt1 = c2 < v1[i];
        const bool lt2 = c2 < v2[i];
        v2[i] = lt1 ? v1[i] : (lt2 ? c2 : v2[i]);
        v1[i] = lt1 ? c2 : v1[i];
        i1[i] = lt1 ? n : i1[i];
      }
    }
  }

  // butterfly top-2 merge across the 16 column lanes
#pragma unroll
  for (int m = 1; m < 16; m <<= 1) {
#pragma unroll
    for (int i = 0; i < 8; ++i) {
      const float ov1 = __shfl_xor(v1[i], m);
      const float ov2 = __shfl_xor(v2[i], m);
      const int oi1 = __shfl_xor(i1[i], m);
      const float nv2 = fminf(fmaxf(v1[i], ov1), fminf(v2[i], ov2));
      const bool take = ov1 < v1[i];
      v1[i] = take ? ov1 : v1[i];
      i1[i] = take ? oi1 : i1[i];
      v2[i] = nv2;
    }
  }
  if (rowl == 0) {  // publish per col-half slot
#pragma unroll
    for (int ta = 0; ta < 2; ++ta)
#pragma unroll
      for (int r = 0; r < 4; ++r) {
        const int row = (((rh << 1) + ta) << 4) + (quad << 2) + r;
        const int i = (ta << 2) + r;
        wsv1[row][ch] = v1[i];
        wsv2[row][ch] = v2[i];
        wsi1[row][ch] = i1[i];
      }
  }
  __syncthreads();

  // ---- cross-half merge, flag ambiguous rows ----
  if (tid < ROWS) {
    float m1 = wsv1[tid][0], m2 = wsv2[tid][0];
    int mi = wsi1[tid][0];
    const float u1 = wsv1[tid][1], u2 = wsv2[tid][1];
    const int j1 = wsi1[tid][1];
    if (u1 < m1) { m2 = fminf(m1, u2); m1 = u1; mi = j1; }
    else { m2 = fminf(m2, u1); }
    win[tid] = mi;
    if (m2 <= m1 + MARGIN) {  // ambiguous: exact rescan required
      const int p = atomicAdd(&qcnt, 1);
      queue[p] = tid;
    }
  }
  __syncthreads();

  // ---- rare fallback: wave-cooperative bit-exact numpy fp32 rescan ----
  const int nq = qcnt;
  for (int qi = wv; qi < nq; qi += 4) {
    const int row = queue[qi];
    const float a2 = a2s[row];
    const float* x = xs[row];  // broadcast LDS reads
    float bd = 3.0e38f;
    int bi = 1 << 30;
#pragma unroll 1
    for (int c = 0; c < 8; ++c) {
      const int k = (c << 6) + lane;
      const float* e = emb + (k << 6);
      float acc = 0.f;
#pragma unroll
      for (int j = 0; j < DIM; ++j) acc = fmaf(x[j], e[j], acc);
      const float tt = a2 + b2g[k];  // fl(a2+b2)
      const float u = 2.0f * acc;    // fl(2ab)
      const float d = tt - u;        // fl(t-u)
      if (d < bd || (d == bd && k < bi)) { bd = d; bi = k; }
    }
#pragma unroll
    for (int m = 1; m < 64; m <<= 1) {  // numpy first-min tie rule
      const float od = __shfl_xor(bd, m);
      const int oi = __shfl_xor(bi, m);
      if (od < bd || (od == bd && oi < bi)) { bd = od; bi = oi; }
    }
    if (lane == 0) win[row] = bi;
  }
  __syncthreads();

  {  // output: fl(x + fl(q-x)), coalesced stores
    const int h = tid & 63, cg = tid >> 6;
    float* obase = out + ((size_t)b << 18) + hw0;
    const float* eW = emb + win[h] * DIM;
#pragma unroll
    for (int i = 0; i < 16; ++i) {
      const int c = cg + (i << 2);
      const float xv = xs[h][c];
      const float qv = eW[c];
      obase[((size_t)c << 12) + h] = xv + (qv - xv);
    }
  }
}

// ---- fallback (R3, passed absmax 0.0): used only if ws too small ----
__global__ __launch_bounds__(256, 2) void vq_exact(
    const float* __restrict__ in, const float* __restrict__ emb,
    float* __restrict__ out, int nvec) {
#pragma clang fp contract(off)
  __shared__ float b2s[NEMB];
  for (int r = threadIdx.x; r < NEMB; r += 256) {
    const float* e = emb + r * DIM;
    float rr[8];
#pragma unroll
    for (int j = 0; j < 8; ++j) {
      float acc = e[j] * e[j];
#pragma unroll
      for (int i = 8; i < DIM; i += 8) acc = acc + e[i + j] * e[i + j];
      rr[j] = acc;
    }
    b2s[r] = ((rr[0] + rr[1]) + (rr[2] + rr[3])) + ((rr[4] + rr[5]) + (rr[6] + rr[7]));
  }
  __syncthreads();
  const int vec = blockIdx.x * 256 + threadIdx.x;
  if (vec >= nvec) return;
  const int b = vec >> 12, hw = vec & 4095;
  const float* xp = in + ((size_t)b << 18) + hw;
  float x[DIM];
#pragma unroll
  for (int j = 0; j < DIM; ++j) x[j] = xp[(size_t)j << 12];
  float a2;
  {
    float rr[8];
#pragma unroll
    for (int j = 0; j < 8; ++j) {
      float acc = x[j] * x[j];
#pragma unroll
      for (int i = 8; i < DIM; i += 8) acc = acc + x[i + j] * x[i + j];
      rr[j] = acc;
    }
    a2 = ((rr[0] + rr[1]) + (rr[2] + rr[3])) + ((rr[4] + rr[5]) + (rr[6] + rr[7]));
  }
  float best = 3.0e38f;
  int bi = 0;
  for (int k0 = 0; k0 < NEMB; k0 += 4) {
    const float *e0 = emb + ((k0 + 0) << 6), *e1 = emb + ((k0 + 1) << 6);
    const float *e2 = emb + ((k0 + 2) << 6), *e3 = emb + ((k0 + 3) << 6);
    float c0 = 0.f, c1 = 0.f, c2 = 0.f, c3 = 0.f;
#pragma unroll
    for (int j = 0; j < DIM; ++j) {
      const float xj = x[j];
      c0 = fmaf(xj, e0[j], c0); c1 = fmaf(xj, e1[j], c1);
      c2 = fmaf(xj, e2[j], c2); c3 = fmaf(xj, e3[j], c3);
    }
    float cc[4] = {c0, c1, c2, c3};
#pragma unroll
    for (int q = 0; q < 4; ++q) {
      const float t = a2 + b2s[k0 + q];
      const float u = 2.0f * cc[q];
      const float d = t - u;
      if (d < best) { best = d; bi = k0 + q; }
    }
  }
  const float* ew = emb + (bi << 6);
  float* op = out + ((size_t)b << 18) + hw;
#pragma unroll
  for (int c = 0; c < DIM; ++c) {
    const float xv = x[c];
    op[(size_t)c << 12] = xv + (ew[c] - xv);
  }
}

extern "C" void kernel_launch(void* const* d_in, const int* in_sizes, int n_in,
                              void* d_out, int out_size, void* d_ws, size_t ws_size,
                              hipStream_t stream) {
  const float* in;
  const float* emb;
  int in_elems;
  if (n_in >= 2 && in_sizes[0] == NEMB * DIM && in_sizes[1] != NEMB * DIM) {
    emb = (const float*)d_in[0]; in = (const float*)d_in[1]; in_elems = in_sizes[1];
  } else {
    in = (const float*)d_in[0]; emb = (const float*)d_in[1]; in_elems = in_sizes[0];
  }
  float* out = (float*)d_out;
  const int nvec = in_elems / DIM;
  const size_t swzB = (size_t)NEMB * DIM * 2 * sizeof(u16);  // hi+lo swizzled
  const size_t need = swzB + NEMB * sizeof(float);

  if (ws_size >= need && d_ws != nullptr && (nvec % ROWS) == 0 &&
      (in_elems % (DIM * 4096)) == 0) {
    u16* swz = (u16*)d_ws;
    float* b2 = (float*)((char*)d_ws + swzB);
    vq_prep<<<dim3(2), dim3(256), 0, stream>>>(emb, swz, b2);
    vq_mfma<<<dim3(nvec / ROWS), dim3(256), 0, stream>>>(in, emb, swz, b2, out);
  } else {
    vq_exact<<<dim3((nvec + 255) / 256), dim3(256), 0, stream>>>(in, emb, out, nvec);
  }
}

// Round 10
// 153.885 us; speedup vs baseline: 2.3050x; 1.2582x over previous
//
#include <hip/hip_runtime.h>

// VectorQuantizer: fp32 buffers, low-precision-valued data. in [32,64,64,64]
// NCHW, emb [512,64], out fp32. np-ref computes distances in fp32 -> argmin
// must match numpy bit-for-bit. Proven numerics (R5/R6/R8/R9, absmax 0.0):
// hi/lo bf16 split (exact products), filter c2=(b2+4)-2*(xh.eh+xh.el+xl.eh),
// MARGIN 1e-4 > 2*filter-error; ambiguity resolved by bit-exact numpy fp32
// replica. R10: kill scattered-global serialization —
//  (1) hot loop tracks top-3 values + top-2 indices, so the common ambiguous
//      case (m2<=m1+MARGIN<m3) is a cheap per-thread exact re-rank of {i1,i2};
//      full wave rescan only when top-3 all within MARGIN (rare);
//  (2) epilogue folds q into xs in place with coalesced emb row reads.

#define NEMB 512
#define DIM 64
#define ROWS 64
#define MARGIN 1.0e-4f

typedef unsigned int u32;
typedef unsigned short u16;
typedef __attribute__((ext_vector_type(8))) short bf16x8;
typedef __attribute__((ext_vector_type(4))) float f32x4;

__device__ __forceinline__ u32 f2bfbits(float f) {  // fp32 -> bf16 bits (RNE)
  u32 u = __float_as_uint(f);
  return (u + 0x7FFFu + ((u >> 16) & 1u)) >> 16;
}
__device__ __forceinline__ float bfbits2f(u32 b) {
  return __uint_as_float(b << 16);
}

// ---- prep: swizzled hi/lo bf16 codebook + exact numpy-replica b2 ----
// off(g,p,f,r,e) = g*2048 + p*1024 + f*512 + r*32 + e   (u16 units)
//   g=row>>4, r=row&15, p=plane(0 hi,1 lo), f=k>>5, e=k&31.
// A wave's 16-row fragment load at fixed (p,f) is 1KB contiguous.
__global__ void vq_prep(const float* __restrict__ emb, u16* __restrict__ swz,
                        float* __restrict__ b2) {
#pragma clang fp contract(off)
  const int n = blockIdx.x * 256 + threadIdx.x;
  if (n >= NEMB) return;
  const float* e = emb + n * DIM;
  float rr[8];
#pragma unroll
  for (int j = 0; j < 8; ++j) {
    float acc = e[j] * e[j];
#pragma unroll
    for (int i = 8; i < DIM; i += 8) acc = acc + e[i + j] * e[i + j];
    rr[j] = acc;
  }
  b2[n] = ((rr[0] + rr[1]) + (rr[2] + rr[3])) + ((rr[4] + rr[5]) + (rr[6] + rr[7]));
  const int g = n >> 4, r = n & 15;
  u16* gb = swz + (g << 11) + (r << 5);
#pragma unroll
  for (int k = 0; k < DIM; ++k) {
    const u32 h = f2bfbits(e[k]);
    const float res = e[k] - bfbits2f(h);  // exact (Sterbenz)
    const int off = ((k >> 5) << 9) + (k & 31);
    gb[off] = (u16)h;                     // hi plane
    gb[1024 + off] = (u16)f2bfbits(res);  // lo plane
  }
}

// ---- main kernel: 64 rows/block.
// wave wv: row-half rh=wv&1 (tiles 2rh,2rh+1), col-half ch=wv>>1 (256 cols).
__global__ __launch_bounds__(256, 1) void vq_mfma(
    const float* __restrict__ in, const float* __restrict__ emb,
    const u16* __restrict__ swz, const float* __restrict__ b2g,
    float* __restrict__ out) {
#pragma clang fp contract(off)
  __shared__ float xs[ROWS][DIM + 2];
  __shared__ float a2s[ROWS];
  __shared__ float b2ps[NEMB];     // fl(b2 + 4) > 0
  __shared__ float wsv1[ROWS][2], wsv2[ROWS][2], wsv3[ROWS][2];
  __shared__ int wsi1[ROWS][2], wsi2[ROWS][2];
  __shared__ int win[ROWS];
  __shared__ int queue[ROWS];
  __shared__ int qcnt;

  const int tid = threadIdx.x;
  const int blk = blockIdx.x;
  const int b = blk >> 6;
  const int hw0 = (blk & 63) << 6;
  const float* xbase = in + ((size_t)b << 18) + hw0;

  for (int i = tid; i < NEMB; i += 256) b2ps[i] = b2g[i] + 4.0f;
  if (tid == 0) qcnt = 0;

  {  // stage x tile (64 consecutive floats per wave = coalesced)
    const int h = tid & 63, cg = tid >> 6;
#pragma unroll
    for (int i = 0; i < 16; ++i) {
      const int c = cg + (i << 2);
      xs[h][c] = xbase[((size_t)c << 12) + h];
    }
  }
  __syncthreads();

  if (tid < ROWS) {  // a2 numpy pairwise-8 replica (re-rank input)
    const float* x = xs[tid];
    float rr[8];
#pragma unroll
    for (int j = 0; j < 8; ++j) {
      float acc = x[j] * x[j];
#pragma unroll
      for (int i = 8; i < DIM; i += 8) acc = acc + x[i + j] * x[i + j];
      rr[j] = acc;
    }
    a2s[tid] = ((rr[0] + rr[1]) + (rr[2] + rr[3])) + ((rr[4] + rr[5]) + (rr[6] + rr[7]));
  }

  const int lane = tid & 63;
  const int wv = tid >> 6;
  const int rh = wv & 1;   // row-half
  const int ch = wv >> 1;  // col-half
  const int rowl = lane & 15;
  const int quad = lane >> 4;

  // A fragments for this wave's 2 row-tiles: A[m=lane&15][k=quad*8+j]
  bf16x8 ah[2][2], al[2][2];
#pragma unroll
  for (int ta = 0; ta < 2; ++ta) {
    const int a = (rh << 1) + ta;
    const float* xr = xs[(a << 4) + rowl];
#pragma unroll
    for (int f = 0; f < 2; ++f) {
      const int k0 = (f << 5) + (quad << 3);
      bf16x8 vh, vl;
#pragma unroll
      for (int j = 0; j < 8; ++j) {
        const float xv = xr[k0 + j];
        const u32 h = f2bfbits(xv);
        const float res = xv - bfbits2f(h);  // exact
        vh[j] = (short)h;
        vl[j] = (short)f2bfbits(res);
      }
      ah[ta][f] = vh;
      al[ta][f] = vl;
    }
  }

  // ---- single pass over 256 cols: streaming top-3 (+top-2 idx) ----
  float v1[8], v2[8], v3[8];
  int i1[8], i2[8];
#pragma unroll
  for (int i = 0; i < 8; ++i) {
    v1[i] = 3.0e38f; v2[i] = 3.0e38f; v3[i] = 3.0e38f; i1[i] = 0; i2[i] = 0;
  }

  const u16* cbase = swz + ((size_t)(ch << 4) << 11);
  const int off = (rowl << 5) + (quad << 3);

  // preload group 0; rolled loop (unroll 1!) with 1-deep clamped prefetch
  bf16x8 nh0 = *(const bf16x8*)(cbase + off);
  bf16x8 nh1 = *(const bf16x8*)(cbase + 512 + off);
  bf16x8 nl0 = *(const bf16x8*)(cbase + 1024 + off);
  bf16x8 nl1 = *(const bf16x8*)(cbase + 1536 + off);

#pragma unroll 1
  for (int t = 0; t < 16; ++t) {
    const bf16x8 bh0 = nh0, bh1 = nh1, bl0 = nl0, bl1 = nl1;
    {  // prefetch next group (clamped: last iter re-loads, harmless)
      const int tn = t < 15 ? t + 1 : 15;
      const u16* gb = cbase + (tn << 11);
      nh0 = *(const bf16x8*)(gb + off);
      nh1 = *(const bf16x8*)(gb + 512 + off);
      nl0 = *(const bf16x8*)(gb + 1024 + off);
      nl1 = *(const bf16x8*)(gb + 1536 + off);
    }
    const int n = (ch << 8) + (t << 4) + rowl;
    const float b2p = b2ps[n];
#pragma unroll
    for (int ta = 0; ta < 2; ++ta) {
      f32x4 acc = {0.f, 0.f, 0.f, 0.f};
      acc = __builtin_amdgcn_mfma_f32_16x16x32_bf16(ah[ta][0], bh0, acc, 0, 0, 0);
      acc = __builtin_amdgcn_mfma_f32_16x16x32_bf16(ah[ta][1], bh1, acc, 0, 0, 0);
      acc = __builtin_amdgcn_mfma_f32_16x16x32_bf16(ah[ta][0], bl0, acc, 0, 0, 0);
      acc = __builtin_amdgcn_mfma_f32_16x16x32_bf16(ah[ta][1], bl1, acc, 0, 0, 0);
      acc = __builtin_amdgcn_mfma_f32_16x16x32_bf16(al[ta][0], bh0, acc, 0, 0, 0);
      acc = __builtin_amdgcn_mfma_f32_16x16x32_bf16(al[ta][1], bh1, acc, 0, 0, 0);
#pragma unroll
      for (int r = 0; r < 4; ++r) {
        const int i = (ta << 2) + r;
        const float c2 = fmaf(-2.0f, acc[r], b2p);
        const bool lt1 = c2 < v1[i];
        const bool lt2 = c2 < v2[i];
        const bool lt3 = c2 < v3[i];
        v3[i] = lt2 ? v2[i] : (lt3 ? c2 : v3[i]);
        v2[i] = lt1 ? v1[i] : (lt2 ? c2 : v2[i]);
        i2[i] = lt1 ? i1[i] : (lt2 ? n : i2[i]);
        v1[i] = lt1 ? c2 : v1[i];
        i1[i] = lt1 ? n : i1[i];
      }
    }
  }

  // butterfly top-3 merge across the 16 column lanes (two indexed inserts +
  // value-only third: exact streaming top-3 since o3 >= merged v2)
#pragma unroll
  for (int m = 1; m < 16; m <<= 1) {
#pragma unroll
    for (int i = 0; i < 8; ++i) {
      const float ov1 = __shfl_xor(v1[i], m);
      const float ov2 = __shfl_xor(v2[i], m);
      const float ov3 = __shfl_xor(v3[i], m);
      const int oi1 = __shfl_xor(i1[i], m);
      const int oi2 = __shfl_xor(i2[i], m);
      bool lt1 = ov1 < v1[i], lt2 = ov1 < v2[i], lt3 = ov1 < v3[i];
      v3[i] = lt2 ? v2[i] : (lt3 ? ov1 : v3[i]);
      v2[i] = lt1 ? v1[i] : (lt2 ? ov1 : v2[i]);
      i2[i] = lt1 ? i1[i] : (lt2 ? oi1 : i2[i]);
      v1[i] = lt1 ? ov1 : v1[i];
      i1[i] = lt1 ? oi1 : i1[i];
      lt1 = ov2 < v1[i]; lt2 = ov2 < v2[i]; lt3 = ov2 < v3[i];
      v3[i] = lt2 ? v2[i] : (lt3 ? ov2 : v3[i]);
      v2[i] = lt1 ? v1[i] : (lt2 ? ov2 : v2[i]);
      i2[i] = lt1 ? i1[i] : (lt2 ? oi2 : i2[i]);
      v1[i] = lt1 ? ov2 : v1[i];
      i1[i] = lt1 ? oi2 : i1[i];
      v3[i] = fminf(v3[i], ov3);
    }
  }
  if (rowl == 0) {  // publish per col-half slot
#pragma unroll
    for (int ta = 0; ta < 2; ++ta)
#pragma unroll
      for (int r = 0; r < 4; ++r) {
        const int row = (((rh << 1) + ta) << 4) + (quad << 2) + r;
        const int i = (ta << 2) + r;
        wsv1[row][ch] = v1[i]; wsv2[row][ch] = v2[i]; wsv3[row][ch] = v3[i];
        wsi1[row][ch] = i1[i]; wsi2[row][ch] = i2[i];
      }
  }
  __syncthreads();

  // ---- cross-half merge + decision ----
  if (tid < ROWS) {
    float m1 = wsv1[tid][0], m2v = wsv2[tid][0], m3 = wsv3[tid][0];
    int j1 = wsi1[tid][0], j2 = wsi2[tid][0];
    const float u1 = wsv1[tid][1], u2 = wsv2[tid][1], u3 = wsv3[tid][1];
    const int k1 = wsi1[tid][1], k2 = wsi2[tid][1];
    bool lt1 = u1 < m1, lt2 = u1 < m2v, lt3 = u1 < m3;
    m3 = lt2 ? m2v : (lt3 ? u1 : m3);
    m2v = lt1 ? m1 : (lt2 ? u1 : m2v);
    j2 = lt1 ? j1 : (lt2 ? k1 : j2);
    m1 = lt1 ? u1 : m1; j1 = lt1 ? k1 : j1;
    lt1 = u2 < m1; lt2 = u2 < m2v; lt3 = u2 < m3;
    m3 = lt2 ? m2v : (lt3 ? u2 : m3);
    m2v = lt1 ? m1 : (lt2 ? u2 : m2v);
    j2 = lt1 ? j1 : (lt2 ? k2 : j2);
    m1 = lt1 ? u2 : m1; j1 = lt1 ? k2 : j1;
    m3 = fminf(m3, u3);

    if (m2v > m1 + MARGIN) {
      win[tid] = j1;  // unambiguous
    } else if (m3 > m1 + MARGIN) {
      // true argmin in {j1,j2}: exact numpy fp32 re-rank, first-min tie rule
      const float a2 = a2s[tid];
      const float* x = xs[tid];
      const float* e1p = emb + (j1 << 6);
      const float* e2p = emb + (j2 << 6);
      float acc1 = 0.f, acc2 = 0.f;
#pragma unroll
      for (int j = 0; j < DIM; ++j) {
        acc1 = fmaf(x[j], e1p[j], acc1);
        acc2 = fmaf(x[j], e2p[j], acc2);
      }
      const float t1 = a2 + b2g[j1];
      const float t2 = a2 + b2g[j2];
      const float d1 = t1 - 2.0f * acc1;
      const float d2 = t2 - 2.0f * acc2;
      win[tid] = (d2 < d1 || (d2 == d1 && j2 < j1)) ? j2 : j1;
    } else {  // >=3 within margin: full exact rescan (rare)
      const int p = atomicAdd(&qcnt, 1);
      queue[p] = tid;
    }
  }
  __syncthreads();

  // ---- rare fallback: wave-cooperative bit-exact numpy fp32 rescan ----
  const int nq = qcnt;
  for (int qi = wv; qi < nq; qi += 4) {
    const int row = queue[qi];
    const float a2 = a2s[row];
    const float* x = xs[row];  // broadcast LDS reads
    float bd = 3.0e38f;
    int bi = 1 << 30;
#pragma unroll 1
    for (int c = 0; c < 8; ++c) {
      const int k = (c << 6) + lane;
      const float* e = emb + (k << 6);
      float acc = 0.f;
#pragma unroll
      for (int j = 0; j < DIM; ++j) acc = fmaf(x[j], e[j], acc);
      const float tt = a2 + b2g[k];  // fl(a2+b2)
      const float u = 2.0f * acc;    // fl(2ab)
      const float d = tt - u;        // fl(t-u)
      if (d < bd || (d == bd && k < bi)) { bd = d; bi = k; }
    }
#pragma unroll
    for (int m = 1; m < 64; m <<= 1) {  // numpy first-min tie rule
      const float od = __shfl_xor(bd, m);
      const int oi = __shfl_xor(bi, m);
      if (od < bd || (od == bd && oi < bi)) { bd = od; bi = oi; }
    }
    if (lane == 0) win[row] = bi;
  }
  __syncthreads();

  {  // fold q into xs in place: coalesced emb row reads, fl(x + fl(q-x))
    const int r0 = wv << 4;
#pragma unroll 1
    for (int r = 0; r < 16; ++r) {
      const int row = r0 + r;
      const float* eW = emb + (win[row] << 6);
      const float xv = xs[row][lane];
      const float qv = eW[lane];
      xs[row][lane] = xv + (qv - xv);
    }
  }
  __syncthreads();

  {  // store: coalesced (lane = h)
    const int h = tid & 63, cg = tid >> 6;
    float* obase = out + ((size_t)b << 18) + hw0;
#pragma unroll
    for (int i = 0; i < 16; ++i) {
      const int c = cg + (i << 2);
      obase[((size_t)c << 12) + h] = xs[h][c];
    }
  }
}

// ---- fallback (R3, passed absmax 0.0): used only if ws too small ----
__global__ __launch_bounds__(256, 2) void vq_exact(
    const float* __restrict__ in, const float* __restrict__ emb,
    float* __restrict__ out, int nvec) {
#pragma clang fp contract(off)
  __shared__ float b2s[NEMB];
  for (int r = threadIdx.x; r < NEMB; r += 256) {
    const float* e = emb + r * DIM;
    float rr[8];
#pragma unroll
    for (int j = 0; j < 8; ++j) {
      float acc = e[j] * e[j];
#pragma unroll
      for (int i = 8; i < DIM; i += 8) acc = acc + e[i + j] * e[i + j];
      rr[j] = acc;
    }
    b2s[r] = ((rr[0] + rr[1]) + (rr[2] + rr[3])) + ((rr[4] + rr[5]) + (rr[6] + rr[7]));
  }
  __syncthreads();
  const int vec = blockIdx.x * 256 + threadIdx.x;
  if (vec >= nvec) return;
  const int b = vec >> 12, hw = vec & 4095;
  const float* xp = in + ((size_t)b << 18) + hw;
  float x[DIM];
#pragma unroll
  for (int j = 0; j < DIM; ++j) x[j] = xp[(size_t)j << 12];
  float a2;
  {
    float rr[8];
#pragma unroll
    for (int j = 0; j < 8; ++j) {
      float acc = x[j] * x[j];
#pragma unroll
      for (int i = 8; i < DIM; i += 8) acc = acc + x[i + j] * x[i + j];
      rr[j] = acc;
    }
    a2 = ((rr[0] + rr[1]) + (rr[2] + rr[3])) + ((rr[4] + rr[5]) + (rr[6] + rr[7]));
  }
  float best = 3.0e38f;
  int bi = 0;
  for (int k0 = 0; k0 < NEMB; k0 += 4) {
    const float *e0 = emb + ((k0 + 0) << 6), *e1 = emb + ((k0 + 1) << 6);
    const float *e2 = emb + ((k0 + 2) << 6), *e3 = emb + ((k0 + 3) << 6);
    float c0 = 0.f, c1 = 0.f, c2 = 0.f, c3 = 0.f;
#pragma unroll
    for (int j = 0; j < DIM; ++j) {
      const float xj = x[j];
      c0 = fmaf(xj, e0[j], c0); c1 = fmaf(xj, e1[j], c1);
      c2 = fmaf(xj, e2[j], c2); c3 = fmaf(xj, e3[j], c3);
    }
    float cc[4] = {c0, c1, c2, c3};
#pragma unroll
    for (int q = 0; q < 4; ++q) {
      const float t = a2 + b2s[k0 + q];
      const float u = 2.0f * cc[q];
      const float d = t - u;
      if (d < best) { best = d; bi = k0 + q; }
    }
  }
  const float* ew = emb + (bi << 6);
  float* op = out + ((size_t)b << 18) + hw;
#pragma unroll
  for (int c = 0; c < DIM; ++c) {
    const float xv = x[c];
    op[(size_t)c << 12] = xv + (ew[c] - xv);
  }
}

extern "C" void kernel_launch(void* const* d_in, const int* in_sizes, int n_in,
                              void* d_out, int out_size, void* d_ws, size_t ws_size,
                              hipStream_t stream) {
  const float* in;
  const float* emb;
  int in_elems;
  if (n_in >= 2 && in_sizes[0] == NEMB * DIM && in_sizes[1] != NEMB * DIM) {
    emb = (const float*)d_in[0]; in = (const float*)d_in[1]; in_elems = in_sizes[1];
  } else {
    in = (const float*)d_in[0]; emb = (const float*)d_in[1]; in_elems = in_sizes[0];
  }
  float* out = (float*)d_out;
  const int nvec = in_elems / DIM;
  const size_t swzB = (size_t)NEMB * DIM * 2 * sizeof(u16);  // hi+lo swizzled
  const size_t need = swzB + NEMB * sizeof(float);

  if (ws_size >= need && d_ws != nullptr && (nvec % ROWS) == 0 &&
      (in_elems % (DIM * 4096)) == 0) {
    u16* swz = (u16*)d_ws;
    float* b2 = (float*)((char*)d_ws + swzB);
    vq_prep<<<dim3(2), dim3(256), 0, stream>>>(emb, swz, b2);
    vq_mfma<<<dim3(nvec / ROWS), dim3(256), 0, stream>>>(in, emb, swz, b2, out);
  } else {
    vq_exact<<<dim3((nvec + 255) / 256), dim3(256), 0, stream>>>(in, emb, out, nvec);
  }
}